// Round 1
// baseline (1444.364 us; speedup 1.0000x reference)
//
#include <hip/hip_runtime.h>
#include <hip/hip_bf16.h>

// Problem constants (from reference)
#define F_DIM 14
#define H1D 16
#define H2D 32
#define H3D 16
#define E_DIM 64
// table size = F_DIM * E_DIM = 896 floats = 224 float4

__device__ __forceinline__ float gelu_exact(float x) {
    // jax.nn.gelu(approximate=False) = 0.5 * x * (1 + erf(x / sqrt(2)))
    return 0.5f * x * (1.0f + erff(x * 0.70710678118654752440f));
}

// Kernel 1: compute the 896-entry table. LayerNorm(1) => normed = beta[f]
// (independent of x), so the whole per-feature MLP is a function of weights only.
// One block, 896 threads; thread t handles (f = t/64, e = t%64). Each thread
// redundantly computes the ~1k-MAC chain for its feature — trivial cost.
__global__ void build_table_kernel(const float* __restrict__ beta,
                                   const float* __restrict__ W1,
                                   const float* __restrict__ b1,
                                   const float* __restrict__ W2,
                                   const float* __restrict__ b2,
                                   const float* __restrict__ W3,
                                   const float* __restrict__ b3,
                                   const float* __restrict__ W4,
                                   const float* __restrict__ b4,
                                   const float* __restrict__ emb,
                                   float* __restrict__ table) {
    const int tid = (int)threadIdx.x;          // 0..895
    const int f = tid >> 6;                    // feature index
    const int e = tid & 63;                    // embedding index
    if (f >= F_DIM) return;

    const float v = beta[f];                   // the LayerNorm(1) output

    float h1[H1D], h2[H2D], h3[H3D];
    #pragma unroll
    for (int k = 0; k < H1D; ++k)
        h1[k] = gelu_exact(v * W1[f * H1D + k] + b1[f * H1D + k]);

    #pragma unroll
    for (int j = 0; j < H2D; ++j) {
        float acc = b2[f * H2D + j];
        #pragma unroll
        for (int k = 0; k < H1D; ++k)
            acc += h1[k] * W2[(f * H1D + k) * H2D + j];
        h2[j] = gelu_exact(acc);
    }

    #pragma unroll
    for (int j = 0; j < H3D; ++j) {
        float acc = b3[f * H3D + j];
        #pragma unroll
        for (int k = 0; k < H2D; ++k)
            acc += h2[k] * W3[(f * H2D + k) * H3D + j];
        h3[j] = gelu_exact(acc);
    }

    float acc = b4[f * E_DIM + e] + emb[f * E_DIM + e];
    #pragma unroll
    for (int m = 0; m < H3D; ++m)
        acc += h3[m] * W4[(f * H3D + m) * E_DIM + e];

    table[tid] = acc;
}

// Kernel 2: broadcast the table over all B*N rows.
// 896 floats/row = 224 float4/row. Grid chosen so (gridDim*blockDim) % 224 == 0,
// so each thread's column (idx % 224) is invariant across grid-stride iterations:
// one table read per thread, then a pure coalesced 16B/lane store loop.
__global__ __launch_bounds__(256) void broadcast_kernel(const float4* __restrict__ table4,
                                                        float4* __restrict__ out4,
                                                        int total4) {
    const int stride = (int)(gridDim.x * blockDim.x);        // multiple of 224
    int idx = (int)(blockIdx.x * blockDim.x + threadIdx.x);
    const int c = idx % 224;                                 // constant per thread
    const float4 tv = table4[c];
    for (; idx < total4; idx += stride)
        out4[idx] = tv;
}

extern "C" void kernel_launch(void* const* d_in, const int* in_sizes, int n_in,
                              void* d_out, int out_size, void* d_ws, size_t ws_size,
                              hipStream_t stream) {
    // setup_inputs order: x, gamma, beta, W1, b1, W2, b2, W3, b3, W4, b4, emb
    const float* beta = (const float*)d_in[2];
    const float* W1   = (const float*)d_in[3];
    const float* b1   = (const float*)d_in[4];
    const float* W2   = (const float*)d_in[5];
    const float* b2   = (const float*)d_in[6];
    const float* W3   = (const float*)d_in[7];
    const float* b3   = (const float*)d_in[8];
    const float* W4   = (const float*)d_in[9];
    const float* b4   = (const float*)d_in[10];
    const float* emb  = (const float*)d_in[11];

    float* out = (float*)d_out;

    // Table scratch: prefer d_ws; fall back to the head of d_out (row 0 of the
    // output IS the table, and the broadcast rewrites it with identical values).
    float* table = (ws_size >= (size_t)(F_DIM * E_DIM * sizeof(float)))
                       ? (float*)d_ws : out;

    build_table_kernel<<<1, F_DIM * E_DIM, 0, stream>>>(
        beta, W1, b1, W2, b2, W3, b3, W4, b4, emb, table);

    const int total4 = out_size / 4;          // 89,600,000 float4 stores
    const int blocks = 3584;                  // 3584*256 = 917504 = 224*4096
    broadcast_kernel<<<blocks, 256, 0, stream>>>(
        (const float4*)table, (float4*)out, total4);
}